// Round 1
// baseline (334.618 us; speedup 1.0000x reference)
//
#include <hip/hip_runtime.h>
#include <stdint.h>

typedef __attribute__((ext_vector_type(8))) short bf16x8;
typedef __attribute__((ext_vector_type(4))) float f32x4;
typedef __attribute__((ext_vector_type(4))) unsigned short u16x4;

static constexpr int Bn = 4, Sn = 2048, Dn = 1024, Hn = 16, HD = 64;
static constexpr int Mrows = Bn * Sn;   // 8192
static constexpr int D3 = 3 * Dn;       // 3072

__device__ __forceinline__ unsigned short f2bf(float f) {
  unsigned int u = __float_as_uint(f);
  u += 0x7FFF + ((u >> 16) & 1);
  return (unsigned short)(u >> 16);
}

__device__ __forceinline__ void gload16(const void* gptr, void* lptr) {
  __builtin_amdgcn_global_load_lds(
      (__attribute__((address_space(1))) void*)gptr,
      (__attribute__((address_space(3))) void*)lptr, 16, 0, 0);
}

__device__ __forceinline__ int swz8(int r) { return (r ^ (r >> 3)) & 7; }
__device__ __forceinline__ int swz4(int r) { return (r ^ (r >> 2)) & 3; }

// ---------------- elementwise f32 -> bf16 ----------------
__global__ void cvt_f32_bf16(const float* __restrict__ in,
                             unsigned short* __restrict__ out, int n) {
  int i = (blockIdx.x * blockDim.x + threadIdx.x) * 4;
  if (i < n) {
    const float4 v = *(const float4*)(in + i);
    u16x4 o;
    o.x = f2bf(v.x); o.y = f2bf(v.y); o.z = f2bf(v.z); o.w = f2bf(v.w);
    *(u16x4*)(out + i) = o;
  }
}

// ---------------- W [K][N] f32 -> W^T [N][K] bf16 ----------------
__global__ void transpose_cvt(const float* __restrict__ W,
                              unsigned short* __restrict__ Wt, int K, int N) {
  __shared__ float tile[32][33];
  const int n0 = blockIdx.x * 32, k0 = blockIdx.y * 32;
  const int tx = threadIdx.x, ty = threadIdx.y;   // block (32,8)
  #pragma unroll
  for (int j = 0; j < 4; j++)
    tile[ty + 8 * j][tx] = W[(size_t)(k0 + ty + 8 * j) * N + n0 + tx];
  __syncthreads();
  #pragma unroll
  for (int j = 0; j < 4; j++)
    Wt[(size_t)(n0 + ty + 8 * j) * K + k0 + tx] = f2bf(tile[tx][ty + 8 * j]);
}

// ---------------- 128x128 bf16 GEMM, C = A[M,K] @ Bt[N,K]^T + bias ----------------
template<bool BF16_OUT>
__global__ __launch_bounds__(256, 2)
void gemm_bt(const unsigned short* __restrict__ A,
             const unsigned short* __restrict__ Bt,
             const float* __restrict__ bias,
             void* __restrict__ Cout, int Mt, int Nt, int Kt) {
  __shared__ __align__(16) unsigned short ldsA[128 * 32];
  __shared__ __align__(16) unsigned short ldsB[128 * 32];
  const int tid  = threadIdx.x;
  const int w    = tid >> 6;
  const int lane = tid & 63;
  const int wr = w >> 1, wc = w & 1;
  const int lrow = lane & 15, lk = lane >> 4;
  const long brow = (long)blockIdx.x * 128;
  const long bcol = (long)blockIdx.y * 128;

  f32x4 acc[4][4] = {};

  const int srow_w = w * 16 + (lane >> 2);  // + i*64 -> staged row
  const int sslot  = lane & 3;

  for (int k0 = 0; k0 < Kt; k0 += 32) {
    __syncthreads();
    #pragma unroll
    for (int i = 0; i < 2; i++) {
      const int r  = i * 64 + srow_w;
      const int ca = sslot ^ swz4(r);   // pre-swizzled global source
      gload16(A  + (size_t)(brow + r) * Kt + k0 + ca * 8, ldsA + i * 2048 + w * 512);
      gload16(Bt + (size_t)(bcol + r) * Kt + k0 + ca * 8, ldsB + i * 2048 + w * 512);
    }
    __syncthreads();
    bf16x8 af[4], bfv[4];
    #pragma unroll
    for (int mt = 0; mt < 4; mt++) {
      const int rr = wr * 64 + mt * 16 + lrow;
      af[mt] = *(const bf16x8*)(ldsA + rr * 32 + ((lk ^ swz4(rr)) * 8));
    }
    #pragma unroll
    for (int nt = 0; nt < 4; nt++) {
      const int rr = wc * 64 + nt * 16 + lrow;
      bfv[nt] = *(const bf16x8*)(ldsB + rr * 32 + ((lk ^ swz4(rr)) * 8));
    }
    #pragma unroll
    for (int mt = 0; mt < 4; mt++)
      #pragma unroll
      for (int nt = 0; nt < 4; nt++)
        acc[mt][nt] = __builtin_amdgcn_mfma_f32_16x16x32_bf16(af[mt], bfv[nt], acc[mt][nt], 0, 0, 0);
  }

  #pragma unroll
  for (int nt = 0; nt < 4; nt++) {
    const long col = bcol + wc * 64 + nt * 16 + lrow;
    const float bv = bias[col];
    #pragma unroll
    for (int mt = 0; mt < 4; mt++) {
      #pragma unroll
      for (int r = 0; r < 4; r++) {
        const long row = brow + wr * 64 + mt * 16 + lk * 4 + r;
        const float v = acc[mt][nt][r] + bv;
        if (BF16_OUT)
          ((unsigned short*)Cout)[row * Nt + col] = f2bf(v);
        else
          ((float*)Cout)[row * Nt + col] = v;
      }
    }
  }
}

// ---------------- flash attention: 128 q-rows/block, 64-kv tiles ----------------
__global__ __launch_bounds__(256, 2)
void attn_fwd(const unsigned short* __restrict__ QKV,
              unsigned short* __restrict__ Out) {
  __shared__ __align__(16) unsigned char smem[32768];
  unsigned char* Klds = smem;            // 8 KB: K [64 kv][64 d]
  unsigned char* Vlds = smem + 8192;     // 8 KB: V^T [64 d][64 kv]
  unsigned char* Plds = smem + 16384;    // 16 KB: per-wave P [32 q][64 kv]

  const int tid  = threadIdx.x;
  const int w    = tid >> 6;
  const int lane = tid & 63;
  const int lrow = lane & 15, lk = lane >> 4;
  const int bh = blockIdx.y;
  const int b  = bh >> 4, h = bh & 15;
  const int qb = ((int)gridDim.x - 1 - (int)blockIdx.x) * 128;

  // Q fragments [mt][c]: A-frag, lane holds Q[qrow=lrow][d = c*32 + lk*8 + j]
  bf16x8 qf[2][2];
  #pragma unroll
  for (int mt = 0; mt < 2; mt++) {
    const size_t qrow = (size_t)(b * Sn + qb + mt * 64 + w * 16 + lrow);
    const unsigned short* qp = QKV + qrow * D3 + h * HD + lk * 8;
    qf[mt][0] = *(const bf16x8*)qp;
    qf[mt][1] = *(const bf16x8*)(qp + 32);
  }

  float mrow[2][4], lsum[2][4];
  f32x4 acco[2][4] = {};
  #pragma unroll
  for (int mt = 0; mt < 2; mt++)
    #pragma unroll
    for (int r = 0; r < 4; r++) { mrow[mt][r] = -__builtin_inff(); lsum[mt][r] = 0.f; }

  unsigned char* pbase = Plds + w * 4096;
  const int kend = qb + 64;

  for (int kb = 0; kb <= kend; kb += 64) {
    __syncthreads();
    // ---- stage K via global_load_lds, source pre-swizzled ----
    {
      const int r0 = w * 8 + (lane >> 3);
      #pragma unroll
      for (int i = 0; i < 2; i++) {
        const int r    = i * 32 + r0;
        const int slot = (lane & 7) ^ swz8(r);
        gload16(QKV + (size_t)(b * Sn + kb + r) * D3 + Dn + h * HD + slot * 8,
                Klds + (size_t)(i * 32 + w * 8) * 128);
      }
    }
    // ---- stage V transposed (reg + swizzled scattered ds_write) ----
    {
      const int tr = tid >> 3;   // 0..31
      const int ts = tid & 7;
      #pragma unroll
      for (int i = 0; i < 2; i++) {
        const int r = i * 32 + tr;   // kv row
        const bf16x8 vv = *(const bf16x8*)(QKV + (size_t)(b * Sn + kb + r) * D3 + 2 * Dn + h * HD + ts * 8);
        #pragma unroll
        for (int j = 0; j < 8; j++) {
          const int d = ts * 8 + j;
          const int byte = d * 128 + ((r * 2) ^ (swz8(d) << 4));
          *(unsigned short*)(Vlds + byte) = (unsigned short)vv[j];
        }
      }
    }
    __syncthreads();

    // ---- S = Q K^T  (K rows read as B-frags: k-contiguous along d) ----
    f32x4 sacc[2][4] = {};
    #pragma unroll
    for (int c = 0; c < 2; c++) {
      #pragma unroll
      for (int n = 0; n < 4; n++) {
        const int kr = n * 16 + lrow;
        const int cc = (lk + 4 * c) ^ swz8(kr);
        const bf16x8 kf = *(const bf16x8*)(Klds + kr * 128 + cc * 16);
        sacc[0][n] = __builtin_amdgcn_mfma_f32_16x16x32_bf16(qf[0][c], kf, sacc[0][n], 0, 0, 0);
        sacc[1][n] = __builtin_amdgcn_mfma_f32_16x16x32_bf16(qf[1][c], kf, sacc[1][n], 0, 0, 0);
      }
    }

    // ---- causal mask + online softmax (rows live in 16-lane groups) ----
    #pragma unroll
    for (int mt = 0; mt < 2; mt++) {
      #pragma unroll
      for (int r = 0; r < 4; r++) {
        const int rg = qb + mt * 64 + w * 16 + lk * 4 + r;
        float sv[4];
        #pragma unroll
        for (int n = 0; n < 4; n++) {
          float s = sacc[mt][n][r] * 0.125f;   // 1/sqrt(64)
          const int cg = kb + n * 16 + lrow;
          if (cg > rg) s = -__builtin_inff();
          sv[n] = s;
        }
        float tmax = fmaxf(fmaxf(sv[0], sv[1]), fmaxf(sv[2], sv[3]));
        #pragma unroll
        for (int msk = 1; msk < 16; msk <<= 1)
          tmax = fmaxf(tmax, __shfl_xor(tmax, msk, 16));
        const float mnew = fmaxf(mrow[mt][r], tmax);
        const float corr = __expf(mrow[mt][r] - mnew);
        float ps = 0.f;
        const int prow = mt * 16 + lk * 4 + r;
        #pragma unroll
        for (int n = 0; n < 4; n++) {
          const float p = __expf(sv[n] - mnew);
          ps += p;
          const int col = n * 16 + lrow;
          *(unsigned short*)(pbase + prow * 128 + ((col * 2) ^ (swz8(prow) << 4))) = f2bf(p);
        }
        #pragma unroll
        for (int msk = 1; msk < 16; msk <<= 1)
          ps += __shfl_xor(ps, msk, 16);
        lsum[mt][r] = lsum[mt][r] * corr + ps;
        mrow[mt][r] = mnew;
        #pragma unroll
        for (int n = 0; n < 4; n++) acco[mt][n][r] *= corr;
      }
    }

    // ---- O += P @ V ----
    #pragma unroll
    for (int c2 = 0; c2 < 2; c2++) {
      bf16x8 pa[2];
      #pragma unroll
      for (int mt = 0; mt < 2; mt++) {
        const int prow = mt * 16 + lrow;
        const int cc = (lk + 4 * c2) ^ swz8(prow);
        pa[mt] = *(const bf16x8*)(pbase + prow * 128 + cc * 16);
      }
      #pragma unroll
      for (int n = 0; n < 4; n++) {
        const int vr = n * 16 + lrow;          // d row of V^T
        const int cc = (lk + 4 * c2) ^ swz8(vr);
        const bf16x8 vb = *(const bf16x8*)(Vlds + vr * 128 + cc * 16);
        acco[0][n] = __builtin_amdgcn_mfma_f32_16x16x32_bf16(pa[0], vb, acco[0][n], 0, 0, 0);
        acco[1][n] = __builtin_amdgcn_mfma_f32_16x16x32_bf16(pa[1], vb, acco[1][n], 0, 0, 0);
      }
    }
  }

  // ---- epilogue: O / l -> bf16, merged-head layout [B*S][D] ----
  #pragma unroll
  for (int mt = 0; mt < 2; mt++) {
    #pragma unroll
    for (int n = 0; n < 4; n++) {
      #pragma unroll
      for (int r = 0; r < 4; r++) {
        const long rowg = qb + mt * 64 + w * 16 + lk * 4 + r;
        const int col = n * 16 + lrow;
        const float v = acco[mt][n][r] / lsum[mt][r];
        Out[(size_t)(b * Sn + rowg) * Dn + h * HD + col] = f2bf(v);
      }
    }
  }
}

// ---------------- tail: string_len -> float ----------------
__global__ void copy_len(const int* __restrict__ slen, float* __restrict__ dst, int n) {
  const int i = threadIdx.x;
  if (i < n) dst[i] = (float)slen[i];
}

extern "C" void kernel_launch(void* const* d_in, const int* in_sizes, int n_in,
                              void* d_out, int out_size, void* d_ws, size_t ws_size,
                              hipStream_t stream) {
  const float* X    = (const float*)d_in[0];
  const int*   slen = (const int*)d_in[1];
  const float* Wqkv = (const float*)d_in[2];
  const float* bqkv = (const float*)d_in[3];
  const float* Wo   = (const float*)d_in[4];
  const float* bo   = (const float*)d_in[5];
  float* out = (float*)d_out;

  char* ws = (char*)d_ws;
  // ws layout (bytes): Xb/Attnb @0 (16 MB) | Wtq @16 MB (6 MB) | Wto (2 MB) | QKVb (48 MB)
  unsigned short* Xb    = (unsigned short*)ws;
  unsigned short* Wtq   = (unsigned short*)(ws + 16777216);
  unsigned short* Wto   = (unsigned short*)(ws + 16777216 + 6291456);
  unsigned short* QKVb  = (unsigned short*)(ws + 16777216 + 6291456 + 2097152);
  unsigned short* Attnb = Xb;   // X is dead after GEMM1; reuse as attention output

  cvt_f32_bf16<<<dim3(8192), dim3(256), 0, stream>>>(X, Xb, Mrows * Dn);
  transpose_cvt<<<dim3(96, 32), dim3(32, 8), 0, stream>>>(Wqkv, Wtq, Dn, D3);
  transpose_cvt<<<dim3(32, 32), dim3(32, 8), 0, stream>>>(Wo, Wto, Dn, Dn);

  gemm_bt<true><<<dim3(64, 24), dim3(256), 0, stream>>>(Xb, Wtq, bqkv, (void*)QKVb, Mrows, D3, Dn);
  attn_fwd<<<dim3(16, 64), dim3(256), 0, stream>>>(QKVb, Attnb);
  gemm_bt<false><<<dim3(64, 8), dim3(256), 0, stream>>>(Attnb, Wto, bo, d_out, Mrows, Dn, Dn);
  copy_len<<<dim3(1), dim3(64), 0, stream>>>(slen, out + (size_t)Mrows * Dn, Bn);
}

// Round 5
// 226.130 us; speedup vs baseline: 1.4798x; 1.4798x over previous
//
#include <hip/hip_runtime.h>
#include <stdint.h>

typedef __attribute__((ext_vector_type(8))) short bf16x8;
typedef __attribute__((ext_vector_type(4))) float f32x4;
typedef __attribute__((ext_vector_type(16))) float f32x16;
typedef __attribute__((ext_vector_type(4))) unsigned short u16x4;

static constexpr int Bn = 4, Sn = 2048, Dn = 1024, Hn = 16, HD = 64;
static constexpr int Mrows = Bn * Sn;   // 8192
static constexpr int D3 = 3 * Dn;       // 3072

__device__ __forceinline__ unsigned short f2bf(float f) {
  unsigned int u = __float_as_uint(f);
  u += 0x7FFF + ((u >> 16) & 1);
  return (unsigned short)(u >> 16);
}

__device__ __forceinline__ void gload16(const void* gptr, void* lptr) {
  __builtin_amdgcn_global_load_lds(
      (__attribute__((address_space(1))) void*)gptr,
      (__attribute__((address_space(3))) void*)lptr, 16, 0, 0);
}

__device__ __forceinline__ int swz8(int r) { return (r ^ (r >> 3)) & 7; }
__device__ __forceinline__ int swz4(int r) { return (r ^ (r >> 2)) & 3; }

__device__ __forceinline__ float vexp2(float x) {
#if __has_builtin(__builtin_amdgcn_exp2f)
  return __builtin_amdgcn_exp2f(x);
#else
  return exp2f(x);
#endif
}

__device__ __forceinline__ unsigned cvtpk(float lo, float hi) {
  unsigned r;
  asm("v_cvt_pk_bf16_f32 %0, %1, %2" : "=v"(r) : "v"(lo), "v"(hi));
  return r;
}

// ---------------- elementwise f32 -> bf16 ----------------
__global__ void cvt_f32_bf16(const float* __restrict__ in,
                             unsigned short* __restrict__ out, int n) {
  int i = (blockIdx.x * blockDim.x + threadIdx.x) * 4;
  if (i < n) {
    const float4 v = *(const float4*)(in + i);
    u16x4 o;
    o.x = f2bf(v.x); o.y = f2bf(v.y); o.z = f2bf(v.z); o.w = f2bf(v.w);
    *(u16x4*)(out + i) = o;
  }
}

// ---------------- W [K][N] f32 -> W^T [N][K] bf16 ----------------
__global__ void transpose_cvt(const float* __restrict__ W,
                              unsigned short* __restrict__ Wt, int K, int N) {
  __shared__ float tile[32][33];
  const int n0 = blockIdx.x * 32, k0 = blockIdx.y * 32;
  const int tx = threadIdx.x, ty = threadIdx.y;   // block (32,8)
  #pragma unroll
  for (int j = 0; j < 4; j++)
    tile[ty + 8 * j][tx] = W[(size_t)(k0 + ty + 8 * j) * N + n0 + tx];
  __syncthreads();
  #pragma unroll
  for (int j = 0; j < 4; j++)
    Wt[(size_t)(n0 + ty + 8 * j) * K + k0 + tx] = f2bf(tile[tx][ty + 8 * j]);
}

// ---------------- 128x128 bf16 GEMM, C = A[M,K] @ Bt[N,K]^T + bias ----------------
template<bool BF16_OUT>
__global__ __launch_bounds__(256, 2)
void gemm_bt(const unsigned short* __restrict__ A,
             const unsigned short* __restrict__ Bt,
             const float* __restrict__ bias,
             void* __restrict__ Cout, int Mt, int Nt, int Kt) {
  __shared__ __align__(16) unsigned short ldsA[128 * 32];
  __shared__ __align__(16) unsigned short ldsB[128 * 32];
  const int tid  = threadIdx.x;
  const int w    = tid >> 6;
  const int lane = tid & 63;
  const int wr = w >> 1, wc = w & 1;
  const int lrow = lane & 15, lk = lane >> 4;
  const long brow = (long)blockIdx.x * 128;
  const long bcol = (long)blockIdx.y * 128;

  f32x4 acc[4][4] = {};

  const int srow_w = w * 16 + (lane >> 2);
  const int sslot  = lane & 3;

  for (int k0 = 0; k0 < Kt; k0 += 32) {
    __syncthreads();
    #pragma unroll
    for (int i = 0; i < 2; i++) {
      const int r  = i * 64 + srow_w;
      const int ca = sslot ^ swz4(r);
      gload16(A  + (size_t)(brow + r) * Kt + k0 + ca * 8, ldsA + i * 2048 + w * 512);
      gload16(Bt + (size_t)(bcol + r) * Kt + k0 + ca * 8, ldsB + i * 2048 + w * 512);
    }
    __syncthreads();
    bf16x8 af[4], bfv[4];
    #pragma unroll
    for (int mt = 0; mt < 4; mt++) {
      const int rr = wr * 64 + mt * 16 + lrow;
      af[mt] = *(const bf16x8*)(ldsA + rr * 32 + ((lk ^ swz4(rr)) * 8));
    }
    #pragma unroll
    for (int nt = 0; nt < 4; nt++) {
      const int rr = wc * 64 + nt * 16 + lrow;
      bfv[nt] = *(const bf16x8*)(ldsB + rr * 32 + ((lk ^ swz4(rr)) * 8));
    }
    #pragma unroll
    for (int mt = 0; mt < 4; mt++)
      #pragma unroll
      for (int nt = 0; nt < 4; nt++)
        acc[mt][nt] = __builtin_amdgcn_mfma_f32_16x16x32_bf16(af[mt], bfv[nt], acc[mt][nt], 0, 0, 0);
  }

  #pragma unroll
  for (int nt = 0; nt < 4; nt++) {
    const long col = bcol + wc * 64 + nt * 16 + lrow;
    const float bv = bias[col];
    #pragma unroll
    for (int mt = 0; mt < 4; mt++) {
      #pragma unroll
      for (int r = 0; r < 4; r++) {
        const long row = brow + wr * 64 + mt * 16 + lk * 4 + r;
        const float v = acc[mt][nt][r] + bv;
        if (BF16_OUT)
          ((unsigned short*)Cout)[row * Nt + col] = f2bf(v);
        else
          ((float*)Cout)[row * Nt + col] = v;
      }
    }
  }
}

// ---------------- flash attention, swapped-QK^T 32x32 structure ----------------
// Block: 4 waves, 128 q rows (32/wave). KV tiles of 64, double-buffered LDS.
// K LDS: [64][64] bf16 row-major, 16B-slot XOR swizzle (swz8) - gload_lds staged.
// V LDS: V^T [64 d][64 kv] bf16, same swizzle, reg-staged scatter write
//        (round-1-verified addressing; tr_read removed pending semantics check).
__global__ __launch_bounds__(256, 2)
void attn_fwd2(const unsigned short* __restrict__ QKV,
               unsigned short* __restrict__ Out) {
  __shared__ __align__(128) unsigned char smem[33280]; // 2 x (8K K + 8K VT) + 512B scratch
  const int tid  = threadIdx.x;
  const int w    = tid >> 6;
  const int lane = tid & 63;
  const int li = lane & 31, hi = lane >> 5;
  const int bh = blockIdx.y;
  const int b  = bh >> 4, h = bh & 15;
  const int qb = ((int)gridDim.x - 1 - (int)blockIdx.x) * 128;
  const int wq = qb + w * 32;
  const int qrow = wq + li;
  float* cscr = (float*)(smem + 32768) + w * 32;

  // Q as B-fragments: lane holds Q[q=li][d = ks*16 + hi*8 + j]
  bf16x8 qf[4];
  {
    const unsigned short* qp = QKV + (size_t)(b * Sn + qrow) * D3 + h * HD + hi * 8;
    #pragma unroll
    for (int ks = 0; ks < 4; ks++) qf[ks] = *(const bf16x8*)(qp + ks * 16);
  }

  f32x16 o0 = {}, o1 = {};
  float m = -3.0e38f, lsum = 0.f;
  const float cexp = 0.18033688011112042f;  // (1/8) * log2(e)

  auto stage = [&](int kb, unsigned char* Kb, unsigned char* Vb) {
    // K: gload_lds, linear dest + inverse-swizzled source
    const int r0 = w * 8 + (lane >> 3);
    #pragma unroll
    for (int i = 0; i < 2; i++) {
      const int r    = i * 32 + r0;
      const int slot = (lane & 7) ^ swz8(r);
      gload16(QKV + (size_t)(b * Sn + kb + r) * D3 + Dn + h * HD + slot * 8,
              Kb + (size_t)(i * 32 + w * 8) * 128);
    }
    // V: reg-staged transpose into VT[d][kv] with 16B-slot swizzle
    const int vr = tid >> 3;        // 0..31
    const int d0 = (tid & 7) * 8;
    #pragma unroll
    for (int i = 0; i < 2; i++) {
      const int kv = i * 32 + vr;
      const bf16x8 vv = *(const bf16x8*)(QKV + (size_t)(b * Sn + kb + kv) * D3 + 2 * Dn + h * HD + d0);
      #pragma unroll
      for (int j = 0; j < 8; j++) {
        const int d = d0 + j;
        *(unsigned short*)(Vb + d * 128 + ((kv * 2) ^ (swz8(d) << 4))) = (unsigned short)vv[j];
      }
    }
  };

  stage(0, smem, smem + 8192);
  __syncthreads();

  const int nt = (qb >> 6) + 2;
  for (int t = 0; t < nt; t++) {
    const int kb  = t << 6;
    const int cur = t & 1;
    unsigned char* Kb = smem + cur * 16384;
    unsigned char* Vb = Kb + 8192;
    if (t + 1 < nt)
      stage(kb + 64, smem + (cur ^ 1) * 16384, smem + (cur ^ 1) * 16384 + 8192);

    if (kb <= wq + 31) {  // wave-uniform: this wave has unmasked rows in this tile
      // ---- S^T = K Q^T : lane holds S^T[kv=crow(r,hi)+32t][q=li] ----
      f32x16 s0 = {}, s1 = {};
      #pragma unroll
      for (int ks = 0; ks < 4; ks++) {
        const int slot = ks * 2 + hi;
        const bf16x8 k0 = *(const bf16x8*)(Kb + li * 128 + ((slot ^ swz8(li)) * 16));
        const bf16x8 k1 = *(const bf16x8*)(Kb + (32 + li) * 128 + ((slot ^ swz8(32 + li)) * 16));
        s0 = __builtin_amdgcn_mfma_f32_32x32x16_bf16(k0, qf[ks], s0, 0, 0, 0);
        s1 = __builtin_amdgcn_mfma_f32_32x32x16_bf16(k1, qf[ks], s1, 0, 0, 0);
      }
      // ---- causal mask: only the diagonal tile needs it ----
      if (kb + 63 > wq) {
        #pragma unroll
        for (int r = 0; r < 16; r++) {
          const int kvl = (r & 3) + 8 * (r >> 2) + 4 * hi;
          if (kb + kvl > qrow)      s0[r] = -3.0e38f;
          if (kb + 32 + kvl > qrow) s1[r] = -3.0e38f;
        }
      }
      // ---- online softmax, lane-local row (pair-combined across hi) ----
      float tmax = -3.0e38f;
      #pragma unroll
      for (int r = 0; r < 16; r++) tmax = fmaxf(tmax, fmaxf(s0[r], s1[r]));
      tmax = fmaxf(tmax, __shfl_xor(tmax, 32));
      if (__any(tmax > m + 44.0f)) {   // 44 raw ~ 8 in log2 units
        const float mn   = fmaxf(m, tmax);
        const float corr = vexp2((m - mn) * cexp);
        m = mn;
        lsum *= corr;
        cscr[li] = corr;  // route corr to C-layout rows via LDS broadcast
        #pragma unroll
        for (int r = 0; r < 16; r++) {
          const float cr = cscr[(r & 3) + 8 * (r >> 2) + 4 * hi];
          o0[r] *= cr; o1[r] *= cr;
        }
      }
      const float mc = m * cexp;
      f32x16 p0, p1;
      float ps = 0.f;
      #pragma unroll
      for (int r = 0; r < 16; r++) { p0[r] = vexp2(fmaf(s0[r], cexp, -mc)); ps += p0[r]; }
      #pragma unroll
      for (int r = 0; r < 16; r++) { p1[r] = vexp2(fmaf(s1[r], cexp, -mc)); ps += p1[r]; }
      lsum += ps;

      // ---- P -> bf16 A-fragments (in-register, partner exchange) ----
      auto mk_pa = [&](const f32x16& p, int base) -> bf16x8 {
        const unsigned a0 = cvtpk(p[base + 0], p[base + 1]);
        const unsigned a1 = cvtpk(p[base + 2], p[base + 3]);
        const unsigned b0 = cvtpk(p[base + 4], p[base + 5]);
        const unsigned b1 = cvtpk(p[base + 6], p[base + 7]);
        const unsigned xa0 = __shfl_xor(a0, 32), xa1 = __shfl_xor(a1, 32);
        const unsigned xb0 = __shfl_xor(b0, 32), xb1 = __shfl_xor(b1, 32);
        union { unsigned u[4]; bf16x8 v; } pu;
        pu.u[0] = hi ? xb0 : a0;
        pu.u[1] = hi ? xb1 : a1;
        pu.u[2] = hi ? b0  : xa0;
        pu.u[3] = hi ? b1  : xa1;
        return pu.v;
      };
      bf16x8 pa[4];
      pa[0] = mk_pa(p0, 0); pa[1] = mk_pa(p0, 8);
      pa[2] = mk_pa(p1, 0); pa[3] = mk_pa(p1, 8);

      // ---- O += P V  (VT rows read as b128, same pattern as K) ----
      #pragma unroll
      for (int k16 = 0; k16 < 4; k16++) {
        const int slot = k16 * 2 + hi;
        const bf16x8 vb0 = *(const bf16x8*)(Vb + li * 128 + ((slot ^ swz8(li)) * 16));
        const bf16x8 vb1 = *(const bf16x8*)(Vb + (32 + li) * 128 + ((slot ^ swz8(32 + li)) * 16));
        o0 = __builtin_amdgcn_mfma_f32_32x32x16_bf16(pa[k16], vb0, o0, 0, 0, 0);
        o1 = __builtin_amdgcn_mfma_f32_32x32x16_bf16(pa[k16], vb1, o1, 0, 0, 0);
      }
    }
    __syncthreads();
  }

  // ---- epilogue: O / l, merged-head store ----
  const float lt = lsum + __shfl_xor(lsum, 32);
  cscr[li] = __builtin_amdgcn_rcpf(lt);
  #pragma unroll
  for (int r = 0; r < 16; r++) {
    const int q = (r & 3) + 8 * (r >> 2) + 4 * hi;
    const float rr = cscr[q];
    unsigned short* op = Out + (size_t)(b * Sn + qb + w * 32 + q) * Dn + h * HD;
    op[li]      = f2bf(o0[r] * rr);
    op[32 + li] = f2bf(o1[r] * rr);
  }
}

// ---------------- tail: string_len -> float ----------------
__global__ void copy_len(const int* __restrict__ slen, float* __restrict__ dst, int n) {
  const int i = threadIdx.x;
  if (i < n) dst[i] = (float)slen[i];
}

extern "C" void kernel_launch(void* const* d_in, const int* in_sizes, int n_in,
                              void* d_out, int out_size, void* d_ws, size_t ws_size,
                              hipStream_t stream) {
  const float* X    = (const float*)d_in[0];
  const int*   slen = (const int*)d_in[1];
  const float* Wqkv = (const float*)d_in[2];
  const float* bqkv = (const float*)d_in[3];
  const float* Wo   = (const float*)d_in[4];
  const float* bo   = (const float*)d_in[5];
  float* out = (float*)d_out;

  char* ws = (char*)d_ws;
  unsigned short* Xb    = (unsigned short*)ws;
  unsigned short* Wtq   = (unsigned short*)(ws + 16777216);
  unsigned short* Wto   = (unsigned short*)(ws + 16777216 + 6291456);
  unsigned short* QKVb  = (unsigned short*)(ws + 16777216 + 6291456 + 2097152);
  unsigned short* Attnb = Xb;

  cvt_f32_bf16<<<dim3(8192), dim3(256), 0, stream>>>(X, Xb, Mrows * Dn);
  transpose_cvt<<<dim3(96, 32), dim3(32, 8), 0, stream>>>(Wqkv, Wtq, Dn, D3);
  transpose_cvt<<<dim3(32, 32), dim3(32, 8), 0, stream>>>(Wo, Wto, Dn, Dn);

  gemm_bt<true><<<dim3(64, 24), dim3(256), 0, stream>>>(Xb, Wtq, bqkv, (void*)QKVb, Mrows, D3, Dn);
  attn_fwd2<<<dim3(16, 64), dim3(256), 0, stream>>>(QKVb, Attnb);
  gemm_bt<false><<<dim3(64, 8), dim3(256), 0, stream>>>(Attnb, Wto, bo, d_out, Mrows, Dn, Dn);
  copy_len<<<dim3(1), dim3(64), 0, stream>>>(slen, out + (size_t)Mrows * Dn, Bn);
}

// Round 6
// 219.796 us; speedup vs baseline: 1.5224x; 1.0288x over previous
//
#include <hip/hip_runtime.h>
#include <stdint.h>

typedef __attribute__((ext_vector_type(8))) short bf16x8;
typedef __attribute__((ext_vector_type(4))) float f32x4;
typedef __attribute__((ext_vector_type(16))) float f32x16;
typedef __attribute__((ext_vector_type(4))) unsigned short u16x4;

static constexpr int Bn = 4, Sn = 2048, Dn = 1024, Hn = 16, HD = 64;
static constexpr int Mrows = Bn * Sn;   // 8192
static constexpr int D3 = 3 * Dn;       // 3072

__device__ __forceinline__ unsigned short f2bf(float f) {
  unsigned int u = __float_as_uint(f);
  u += 0x7FFF + ((u >> 16) & 1);
  return (unsigned short)(u >> 16);
}

__device__ __forceinline__ void gload16(const void* gptr, void* lptr) {
  __builtin_amdgcn_global_load_lds(
      (__attribute__((address_space(1))) void*)gptr,
      (__attribute__((address_space(3))) void*)lptr, 16, 0, 0);
}

__device__ __forceinline__ int swz8(int r) { return (r ^ (r >> 3)) & 7; }
__device__ __forceinline__ int swz4(int r) { return (r ^ (r >> 2)) & 3; }

__device__ __forceinline__ float vexp2(float x) {
#if __has_builtin(__builtin_amdgcn_exp2f)
  return __builtin_amdgcn_exp2f(x);
#else
  return exp2f(x);
#endif
}

__device__ __forceinline__ unsigned cvtpk(float lo, float hi) {
  unsigned r;
  asm("v_cvt_pk_bf16_f32 %0, %1, %2" : "=v"(r) : "v"(lo), "v"(hi));
  return r;
}

__device__ __forceinline__ float lanepull(float v, int srclane) {
  return __int_as_float(__builtin_amdgcn_ds_bpermute(srclane * 4, __float_as_int(v)));
}

// ---------------- elementwise f32 -> bf16 ----------------
__global__ void cvt_f32_bf16(const float* __restrict__ in,
                             unsigned short* __restrict__ out, int n) {
  int i = (blockIdx.x * blockDim.x + threadIdx.x) * 4;
  if (i < n) {
    const float4 v = *(const float4*)(in + i);
    u16x4 o;
    o.x = f2bf(v.x); o.y = f2bf(v.y); o.z = f2bf(v.z); o.w = f2bf(v.w);
    *(u16x4*)(out + i) = o;
  }
}

// ---------------- W [K][N] f32 -> W^T [N][K] bf16 ----------------
__global__ void transpose_cvt(const float* __restrict__ W,
                              unsigned short* __restrict__ Wt, int K, int N) {
  __shared__ float tile[32][33];
  const int n0 = blockIdx.x * 32, k0 = blockIdx.y * 32;
  const int tx = threadIdx.x, ty = threadIdx.y;   // block (32,8)
  #pragma unroll
  for (int j = 0; j < 4; j++)
    tile[ty + 8 * j][tx] = W[(size_t)(k0 + ty + 8 * j) * N + n0 + tx];
  __syncthreads();
  #pragma unroll
  for (int j = 0; j < 4; j++)
    Wt[(size_t)(n0 + ty + 8 * j) * K + k0 + tx] = f2bf(tile[tx][ty + 8 * j]);
}

// ---------------- 128x128 bf16 GEMM, C = A[M,K] @ Bt[N,K]^T + bias ----------------
template<bool BF16_OUT>
__global__ __launch_bounds__(256, 2)
void gemm_bt(const unsigned short* __restrict__ A,
             const unsigned short* __restrict__ Bt,
             const float* __restrict__ bias,
             void* __restrict__ Cout, int Mt, int Nt, int Kt) {
  __shared__ __align__(16) unsigned short ldsA[128 * 32];
  __shared__ __align__(16) unsigned short ldsB[128 * 32];
  const int tid  = threadIdx.x;
  const int w    = tid >> 6;
  const int lane = tid & 63;
  const int wr = w >> 1, wc = w & 1;
  const int lrow = lane & 15, lk = lane >> 4;
  const long brow = (long)blockIdx.x * 128;
  const long bcol = (long)blockIdx.y * 128;

  f32x4 acc[4][4] = {};

  const int srow_w = w * 16 + (lane >> 2);
  const int sslot  = lane & 3;

  for (int k0 = 0; k0 < Kt; k0 += 32) {
    __syncthreads();
    #pragma unroll
    for (int i = 0; i < 2; i++) {
      const int r  = i * 64 + srow_w;
      const int ca = sslot ^ swz4(r);
      gload16(A  + (size_t)(brow + r) * Kt + k0 + ca * 8, ldsA + i * 2048 + w * 512);
      gload16(Bt + (size_t)(bcol + r) * Kt + k0 + ca * 8, ldsB + i * 2048 + w * 512);
    }
    __syncthreads();
    bf16x8 af[4], bfv[4];
    #pragma unroll
    for (int mt = 0; mt < 4; mt++) {
      const int rr = wr * 64 + mt * 16 + lrow;
      af[mt] = *(const bf16x8*)(ldsA + rr * 32 + ((lk ^ swz4(rr)) * 8));
    }
    #pragma unroll
    for (int nt = 0; nt < 4; nt++) {
      const int rr = wc * 64 + nt * 16 + lrow;
      bfv[nt] = *(const bf16x8*)(ldsB + rr * 32 + ((lk ^ swz4(rr)) * 8));
    }
    #pragma unroll
    for (int mt = 0; mt < 4; mt++)
      #pragma unroll
      for (int nt = 0; nt < 4; nt++)
        acc[mt][nt] = __builtin_amdgcn_mfma_f32_16x16x32_bf16(af[mt], bfv[nt], acc[mt][nt], 0, 0, 0);
  }

  #pragma unroll
  for (int nt = 0; nt < 4; nt++) {
    const long col = bcol + wc * 64 + nt * 16 + lrow;
    const float bv = bias[col];
    #pragma unroll
    for (int mt = 0; mt < 4; mt++) {
      #pragma unroll
      for (int r = 0; r < 4; r++) {
        const long row = brow + wr * 64 + mt * 16 + lk * 4 + r;
        const float v = acc[mt][nt][r] + bv;
        if (BF16_OUT)
          ((unsigned short*)Cout)[row * Nt + col] = f2bf(v);
        else
          ((float*)Cout)[row * Nt + col] = v;
      }
    }
  }
}

// ---------------- flash attention, swapped-QK^T, paired q-tiles ----------------
// Block: 4 waves. Waves 0,1 -> q-tile qhi=31-p (64 rows); waves 2,3 -> q-tile
// qlo=p. Both share one KV stream (nt = qhi+1 tiles) -> uniform compute per
// block (33 tile-units) for load balance. LDS exactly 32 KiB -> 5 blocks/CU.
// K LDS: [64][64] bf16 swz8-swizzled, gload_lds staged.
// V LDS: V^T [64 d][64 kv], same swizzle, reg-staged scatter write.
__global__ __launch_bounds__(256, 2)
void attn_fwd2(const unsigned short* __restrict__ QKV,
               unsigned short* __restrict__ Out) {
  __shared__ __align__(128) unsigned char smem[32768]; // 2 x (8K K + 8K VT)
  const int tid  = threadIdx.x;
  const int w    = tid >> 6;
  const int lane = tid & 63;
  const int li = lane & 31, hi = lane >> 5;
  const int bh = blockIdx.y;
  const int b  = bh >> 4, h = bh & 15;
  const int p  = blockIdx.x;            // pair index 0..15, p=0 heaviest (dispatches first)
  const int qhi = 31 - p, qlo = p;      // 64-row q-tile indices
  const int wq = (w < 2) ? (qhi * 64 + w * 32) : (qlo * 64 + (w - 2) * 32);
  const int qrow = wq + li;

  // Q as B-fragments: lane holds Q[q=li][d = ks*16 + hi*8 + j]
  bf16x8 qf[4];
  {
    const unsigned short* qp = QKV + (size_t)(b * Sn + qrow) * D3 + h * HD + hi * 8;
    #pragma unroll
    for (int ks = 0; ks < 4; ks++) qf[ks] = *(const bf16x8*)(qp + ks * 16);
  }

  f32x16 o0 = {}, o1 = {};
  float m = -3.0e38f, lsum = 0.f;
  const float cexp = 0.18033688011112042f;  // (1/8) * log2(e)

  auto stage = [&](int kb, unsigned char* Kb, unsigned char* Vb) {
    // K: gload_lds, linear dest + inverse-swizzled source
    const int r0 = w * 8 + (lane >> 3);
    #pragma unroll
    for (int i = 0; i < 2; i++) {
      const int r    = i * 32 + r0;
      const int slot = (lane & 7) ^ swz8(r);
      gload16(QKV + (size_t)(b * Sn + kb + r) * D3 + Dn + h * HD + slot * 8,
              Kb + (size_t)(i * 32 + w * 8) * 128);
    }
    // V: reg-staged transpose into VT[d][kv] with 16B-slot swizzle
    const int vr = tid >> 3;        // 0..31
    const int d0 = (tid & 7) * 8;
    #pragma unroll
    for (int i = 0; i < 2; i++) {
      const int kv = i * 32 + vr;
      const bf16x8 vv = *(const bf16x8*)(QKV + (size_t)(b * Sn + kb + kv) * D3 + 2 * Dn + h * HD + d0);
      #pragma unroll
      for (int j = 0; j < 8; j++) {
        const int d = d0 + j;
        *(unsigned short*)(Vb + d * 128 + ((kv * 2) ^ (swz8(d) << 4))) = (unsigned short)vv[j];
      }
    }
  };

  stage(0, smem, smem + 8192);
  __syncthreads();

  const int nt = qhi + 1;               // kv tiles needed by the heavy q-tile
  for (int t = 0; t < nt; t++) {
    const int kb  = t << 6;
    const int cur = t & 1;
    unsigned char* Kb = smem + cur * 16384;
    unsigned char* Vb = Kb + 8192;
    if (t + 1 < nt)
      stage(kb + 64, smem + (cur ^ 1) * 16384, smem + (cur ^ 1) * 16384 + 8192);

    if (kb <= wq + 31) {  // wave-uniform: this wave has unmasked rows in this tile
      // ---- S^T = K Q^T : lane holds S^T[kv=crow(r,hi)+32t][q=li] ----
      f32x16 s0 = {}, s1 = {};
      #pragma unroll
      for (int ks = 0; ks < 4; ks++) {
        const int slot = ks * 2 + hi;
        const bf16x8 k0 = *(const bf16x8*)(Kb + li * 128 + ((slot ^ swz8(li)) * 16));
        const bf16x8 k1 = *(const bf16x8*)(Kb + (32 + li) * 128 + ((slot ^ swz8(32 + li)) * 16));
        s0 = __builtin_amdgcn_mfma_f32_32x32x16_bf16(k0, qf[ks], s0, 0, 0, 0);
        s1 = __builtin_amdgcn_mfma_f32_32x32x16_bf16(k1, qf[ks], s1, 0, 0, 0);
      }
      // ---- causal mask: only the diagonal tile needs it ----
      if (kb + 63 > wq) {
        #pragma unroll
        for (int r = 0; r < 16; r++) {
          const int kvl = (r & 3) + 8 * (r >> 2) + 4 * hi;
          if (kb + kvl > qrow)      s0[r] = -3.0e38f;
          if (kb + 32 + kvl > qrow) s1[r] = -3.0e38f;
        }
      }
      // ---- online softmax, lane-local row (pair-combined across hi) ----
      float tmax = -3.0e38f;
      #pragma unroll
      for (int r = 0; r < 16; r++) tmax = fmaxf(tmax, fmaxf(s0[r], s1[r]));
      tmax = fmaxf(tmax, __shfl_xor(tmax, 32));
      if (__any(tmax > m + 44.0f)) {   // 44 raw ~ 8 in log2 units
        const float mn   = fmaxf(m, tmax);
        const float corr = vexp2((m - mn) * cexp);
        m = mn;
        lsum *= corr;
        #pragma unroll
        for (int r = 0; r < 16; r++) {
          const float cr = lanepull(corr, (r & 3) + 8 * (r >> 2) + 4 * hi);
          o0[r] *= cr; o1[r] *= cr;
        }
      }
      const float mc = m * cexp;
      f32x16 p0, p1;
      float ps = 0.f;
      #pragma unroll
      for (int r = 0; r < 16; r++) { p0[r] = vexp2(fmaf(s0[r], cexp, -mc)); ps += p0[r]; }
      #pragma unroll
      for (int r = 0; r < 16; r++) { p1[r] = vexp2(fmaf(s1[r], cexp, -mc)); ps += p1[r]; }
      lsum += ps;

      // ---- P -> bf16 A-fragments (in-register, partner exchange) ----
      auto mk_pa = [&](const f32x16& pp, int base) -> bf16x8 {
        const unsigned a0 = cvtpk(pp[base + 0], pp[base + 1]);
        const unsigned a1 = cvtpk(pp[base + 2], pp[base + 3]);
        const unsigned b0 = cvtpk(pp[base + 4], pp[base + 5]);
        const unsigned b1 = cvtpk(pp[base + 6], pp[base + 7]);
        const unsigned xa0 = __shfl_xor(a0, 32), xa1 = __shfl_xor(a1, 32);
        const unsigned xb0 = __shfl_xor(b0, 32), xb1 = __shfl_xor(b1, 32);
        union { unsigned u[4]; bf16x8 v; } pu;
        pu.u[0] = hi ? xb0 : a0;
        pu.u[1] = hi ? xb1 : a1;
        pu.u[2] = hi ? b0  : xa0;
        pu.u[3] = hi ? b1  : xa1;
        return pu.v;
      };
      bf16x8 pa[4];
      pa[0] = mk_pa(p0, 0); pa[1] = mk_pa(p0, 8);
      pa[2] = mk_pa(p1, 0); pa[3] = mk_pa(p1, 8);

      // ---- O += P V  (VT rows read as b128, same pattern as K) ----
      #pragma unroll
      for (int k16 = 0; k16 < 4; k16++) {
        const int slot = k16 * 2 + hi;
        const bf16x8 vb0 = *(const bf16x8*)(Vb + li * 128 + ((slot ^ swz8(li)) * 16));
        const bf16x8 vb1 = *(const bf16x8*)(Vb + (32 + li) * 128 + ((slot ^ swz8(32 + li)) * 16));
        o0 = __builtin_amdgcn_mfma_f32_32x32x16_bf16(pa[k16], vb0, o0, 0, 0, 0);
        o1 = __builtin_amdgcn_mfma_f32_32x32x16_bf16(pa[k16], vb1, o1, 0, 0, 0);
      }
    }
    __syncthreads();
  }

  // ---- epilogue: O / l, merged-head store ----
  const float lt = lsum + __shfl_xor(lsum, 32);
  const float rl = __builtin_amdgcn_rcpf(lt);
  #pragma unroll
  for (int r = 0; r < 16; r++) {
    const int q = (r & 3) + 8 * (r >> 2) + 4 * hi;
    const float rr = lanepull(rl, q);
    unsigned short* op = Out + (size_t)(b * Sn + wq + q) * Dn + h * HD;
    op[li]      = f2bf(o0[r] * rr);
    op[32 + li] = f2bf(o1[r] * rr);
  }
}

// ---------------- tail: string_len -> float ----------------
__global__ void copy_len(const int* __restrict__ slen, float* __restrict__ dst, int n) {
  const int i = threadIdx.x;
  if (i < n) dst[i] = (float)slen[i];
}

extern "C" void kernel_launch(void* const* d_in, const int* in_sizes, int n_in,
                              void* d_out, int out_size, void* d_ws, size_t ws_size,
                              hipStream_t stream) {
  const float* X    = (const float*)d_in[0];
  const int*   slen = (const int*)d_in[1];
  const float* Wqkv = (const float*)d_in[2];
  const float* bqkv = (const float*)d_in[3];
  const float* Wo   = (const float*)d_in[4];
  const float* bo   = (const float*)d_in[5];
  float* out = (float*)d_out;

  char* ws = (char*)d_ws;
  unsigned short* Xb    = (unsigned short*)ws;
  unsigned short* Wtq   = (unsigned short*)(ws + 16777216);
  unsigned short* Wto   = (unsigned short*)(ws + 16777216 + 6291456);
  unsigned short* QKVb  = (unsigned short*)(ws + 16777216 + 6291456 + 2097152);
  unsigned short* Attnb = Xb;

  cvt_f32_bf16<<<dim3(8192), dim3(256), 0, stream>>>(X, Xb, Mrows * Dn);
  transpose_cvt<<<dim3(96, 32), dim3(32, 8), 0, stream>>>(Wqkv, Wtq, Dn, D3);
  transpose_cvt<<<dim3(32, 32), dim3(32, 8), 0, stream>>>(Wo, Wto, Dn, Dn);

  gemm_bt<true><<<dim3(64, 24), dim3(256), 0, stream>>>(Xb, Wtq, bqkv, (void*)QKVb, Mrows, D3, Dn);
  attn_fwd2<<<dim3(16, 64), dim3(256), 0, stream>>>(QKVb, Attnb);
  gemm_bt<false><<<dim3(64, 8), dim3(256), 0, stream>>>(Attnb, Wto, bo, d_out, Mrows, Dn, Dn);
  copy_len<<<dim3(1), dim3(64), 0, stream>>>(slen, out + (size_t)Mrows * Dn, Bn);
}

// Round 7
// 193.963 us; speedup vs baseline: 1.7252x; 1.1332x over previous
//
#include <hip/hip_runtime.h>
#include <stdint.h>

typedef __attribute__((ext_vector_type(8))) short bf16x8;
typedef __attribute__((ext_vector_type(4))) float f32x4;
typedef __attribute__((ext_vector_type(16))) float f32x16;
typedef __attribute__((ext_vector_type(4))) unsigned short u16x4;

static constexpr int Bn = 4, Sn = 2048, Dn = 1024, Hn = 16, HD = 64;
static constexpr int Mrows = Bn * Sn;   // 8192
static constexpr int D3 = 3 * Dn;       // 3072

__device__ __forceinline__ unsigned short f2bf(float f) {
  unsigned int u = __float_as_uint(f);
  u += 0x7FFF + ((u >> 16) & 1);
  return (unsigned short)(u >> 16);
}

__device__ __forceinline__ void gload16(const void* gptr, void* lptr) {
  __builtin_amdgcn_global_load_lds(
      (__attribute__((address_space(1))) void*)gptr,
      (__attribute__((address_space(3))) void*)lptr, 16, 0, 0);
}

__device__ __forceinline__ int swz8(int r) { return (r ^ (r >> 3)) & 7; }
__device__ __forceinline__ int swz4(int r) { return (r ^ (r >> 2)) & 3; }

__device__ __forceinline__ float vexp2(float x) {
#if __has_builtin(__builtin_amdgcn_exp2f)
  return __builtin_amdgcn_exp2f(x);
#else
  return exp2f(x);
#endif
}

__device__ __forceinline__ unsigned cvtpk(float lo, float hi) {
  unsigned r;
  asm("v_cvt_pk_bf16_f32 %0, %1, %2" : "=v"(r) : "v"(lo), "v"(hi));
  return r;
}

__device__ __forceinline__ float lanepull(float v, int srclane) {
  return __int_as_float(__builtin_amdgcn_ds_bpermute(srclane * 4, __float_as_int(v)));
}

// ---------------- elementwise f32 -> bf16 ----------------
__global__ void cvt_f32_bf16(const float* __restrict__ in,
                             unsigned short* __restrict__ out, int n) {
  int i = (blockIdx.x * blockDim.x + threadIdx.x) * 4;
  if (i < n) {
    const float4 v = *(const float4*)(in + i);
    u16x4 o;
    o.x = f2bf(v.x); o.y = f2bf(v.y); o.z = f2bf(v.z); o.w = f2bf(v.w);
    *(u16x4*)(out + i) = o;
  }
}

// ---------------- W [K][N] f32 -> W^T [N][K] bf16 ----------------
__global__ void transpose_cvt(const float* __restrict__ W,
                              unsigned short* __restrict__ Wt, int K, int N) {
  __shared__ float tile[32][33];
  const int n0 = blockIdx.x * 32, k0 = blockIdx.y * 32;
  const int tx = threadIdx.x, ty = threadIdx.y;   // block (32,8)
  #pragma unroll
  for (int j = 0; j < 4; j++)
    tile[ty + 8 * j][tx] = W[(size_t)(k0 + ty + 8 * j) * N + n0 + tx];
  __syncthreads();
  #pragma unroll
  for (int j = 0; j < 4; j++)
    Wt[(size_t)(n0 + ty + 8 * j) * K + k0 + tx] = f2bf(tile[tx][ty + 8 * j]);
}

// ---------------- 128x128 bf16 GEMM, C = A[M,K] @ Bt[N,K]^T + bias ----------------
template<bool BF16_OUT>
__global__ __launch_bounds__(256, 2)
void gemm_bt(const unsigned short* __restrict__ A,
             const unsigned short* __restrict__ Bt,
             const float* __restrict__ bias,
             void* __restrict__ Cout, int Mt, int Nt, int Kt) {
  __shared__ __align__(16) unsigned short ldsA[128 * 32];
  __shared__ __align__(16) unsigned short ldsB[128 * 32];
  const int tid  = threadIdx.x;
  const int w    = tid >> 6;
  const int lane = tid & 63;
  const int wr = w >> 1, wc = w & 1;
  const int lrow = lane & 15, lk = lane >> 4;
  const long brow = (long)blockIdx.x * 128;
  const long bcol = (long)blockIdx.y * 128;

  f32x4 acc[4][4] = {};

  const int srow_w = w * 16 + (lane >> 2);
  const int sslot  = lane & 3;

  for (int k0 = 0; k0 < Kt; k0 += 32) {
    __syncthreads();
    #pragma unroll
    for (int i = 0; i < 2; i++) {
      const int r  = i * 64 + srow_w;
      const int ca = sslot ^ swz4(r);
      gload16(A  + (size_t)(brow + r) * Kt + k0 + ca * 8, ldsA + i * 2048 + w * 512);
      gload16(Bt + (size_t)(bcol + r) * Kt + k0 + ca * 8, ldsB + i * 2048 + w * 512);
    }
    __syncthreads();
    bf16x8 af[4], bfv[4];
    #pragma unroll
    for (int mt = 0; mt < 4; mt++) {
      const int rr = wr * 64 + mt * 16 + lrow;
      af[mt] = *(const bf16x8*)(ldsA + rr * 32 + ((lk ^ swz4(rr)) * 8));
    }
    #pragma unroll
    for (int nt = 0; nt < 4; nt++) {
      const int rr = wc * 64 + nt * 16 + lrow;
      bfv[nt] = *(const bf16x8*)(ldsB + rr * 32 + ((lk ^ swz4(rr)) * 8));
    }
    #pragma unroll
    for (int mt = 0; mt < 4; mt++)
      #pragma unroll
      for (int nt = 0; nt < 4; nt++)
        acc[mt][nt] = __builtin_amdgcn_mfma_f32_16x16x32_bf16(af[mt], bfv[nt], acc[mt][nt], 0, 0, 0);
  }

  #pragma unroll
  for (int nt = 0; nt < 4; nt++) {
    const long col = bcol + wc * 64 + nt * 16 + lrow;
    const float bv = bias[col];
    #pragma unroll
    for (int mt = 0; mt < 4; mt++) {
      #pragma unroll
      for (int r = 0; r < 4; r++) {
        const long row = brow + wr * 64 + mt * 16 + lk * 4 + r;
        const float v = acc[mt][nt][r] + bv;
        if (BF16_OUT)
          ((unsigned short*)Cout)[row * Nt + col] = f2bf(v);
        else
          ((float*)Cout)[row * Nt + col] = v;
      }
    }
  }
}

// ---------------- flash attention, swapped-QK^T, 8-wave paired blocks ----------------
// Block: 8 waves (512 thr), one KV stream. Waves 0-3 -> heavy q-subtiles
// (63-4p-w)*32; waves 4-7 -> light (4p+w-4)*32. Uniform work per block.
// Grid (bh=64, p=8): same-KV blocks land on one XCD (L2-local KV).
// T14 split: V(t+1) global->reg issued before compute, ds_write after.
// K LDS: [64][64] bf16 swz8-swizzled, gload_lds staged (linear dest).
// V LDS: V^T [64 d][64 kv], same swizzle, reg-staged scatter write.
__global__ __launch_bounds__(512, 2)
void attn_fwd2(const unsigned short* __restrict__ QKV,
               unsigned short* __restrict__ Out) {
  __shared__ __align__(128) unsigned char smem[32768]; // 2 x (8K K + 8K VT)
  const int tid  = threadIdx.x;
  const int w    = tid >> 6;
  const int lane = tid & 63;
  const int li = lane & 31, hi = lane >> 5;
  const int bh = blockIdx.x;
  const int b  = bh >> 4, h = bh & 15;
  const int pb = blockIdx.y;            // pair-group 0..7
  const int qs = (w < 4) ? (63 - 4 * pb - w) : (4 * pb + (w - 4));  // 32-row q-subtile
  const int wq = qs * 32;
  const int qrow = wq + li;

  // Q as B-fragments: lane holds Q[q=li][d = ks*16 + hi*8 + j]
  bf16x8 qf[4];
  {
    const unsigned short* qp = QKV + (size_t)(b * Sn + qrow) * D3 + h * HD + hi * 8;
    #pragma unroll
    for (int ks = 0; ks < 4; ks++) qf[ks] = *(const bf16x8*)(qp + ks * 16);
  }

  f32x16 o0 = {}, o1 = {};
  float m = -3.0e38f, lsum = 0.f;
  const float cexp = 0.18033688011112042f;  // (1/8) * log2(e)

  // K stage: each wave stages rows w*8..w*8+7 (1 KB), linear dest + pre-swz src
  auto kstage = [&](int kb, unsigned char* Kb) {
    const int r    = w * 8 + (lane >> 3);
    const int slot = (lane & 7) ^ swz8(r);
    gload16(QKV + (size_t)(b * Sn + kb + r) * D3 + Dn + h * HD + slot * 8,
            Kb + w * 1024);
  };
  const int vkv = tid >> 3;          // 0..63
  const int vd0 = (tid & 7) * 8;
  auto vload = [&](int kb) -> bf16x8 {
    return *(const bf16x8*)(QKV + (size_t)(b * Sn + kb + vkv) * D3 + 2 * Dn + h * HD + vd0);
  };
  auto vwrite = [&](bf16x8 vv, unsigned char* Vb) {
    #pragma unroll
    for (int j = 0; j < 8; j++) {
      const int d = vd0 + j;
      *(unsigned short*)(Vb + d * 128 + ((vkv * 2) ^ (swz8(d) << 4))) = (unsigned short)vv[j];
    }
  };

  kstage(0, smem);
  vwrite(vload(0), smem + 8192);
  __syncthreads();

  const int nt = ((63 - 4 * pb) >> 1) + 1;  // tiles for heaviest subtile
  for (int t = 0; t < nt; t++) {
    const int kb  = t << 6;
    const int cur = t & 1;
    unsigned char* Kb = smem + cur * 16384;
    unsigned char* Vb = Kb + 8192;
    const bool pre = (t + 1 < nt);
    bf16x8 vnext;
    if (pre) {
      kstage(kb + 64, smem + (cur ^ 1) * 16384);   // async into LDS
      vnext = vload(kb + 64);                      // async into regs (used post-compute)
    }

    if (kb <= wq + 31) {  // wave-uniform activity test
      // ---- S^T = K Q^T : lane holds S^T[kv=crow(r,hi)+32t][q=li] ----
      f32x16 s0 = {}, s1 = {};
      #pragma unroll
      for (int ks = 0; ks < 4; ks++) {
        const int slot = ks * 2 + hi;
        const bf16x8 k0 = *(const bf16x8*)(Kb + li * 128 + ((slot ^ swz8(li)) * 16));
        const bf16x8 k1 = *(const bf16x8*)(Kb + (32 + li) * 128 + ((slot ^ swz8(32 + li)) * 16));
        s0 = __builtin_amdgcn_mfma_f32_32x32x16_bf16(k0, qf[ks], s0, 0, 0, 0);
        s1 = __builtin_amdgcn_mfma_f32_32x32x16_bf16(k1, qf[ks], s1, 0, 0, 0);
      }
      // ---- causal mask: only the diagonal tile needs it ----
      if (kb + 63 > wq) {
        #pragma unroll
        for (int r = 0; r < 16; r++) {
          const int kvl = (r & 3) + 8 * (r >> 2) + 4 * hi;
          if (kb + kvl > qrow)      s0[r] = -3.0e38f;
          if (kb + 32 + kvl > qrow) s1[r] = -3.0e38f;
        }
      }
      // ---- online softmax, lane-local row ----
      float tmax = -3.0e38f;
      #pragma unroll
      for (int r = 0; r < 16; r++) tmax = fmaxf(tmax, fmaxf(s0[r], s1[r]));
      tmax = fmaxf(tmax, __shfl_xor(tmax, 32));
      if (__any(tmax > m + 44.0f)) {   // defer-max, 44 raw ~ 8 log2 units
        const float mn   = fmaxf(m, tmax);
        const float corr = vexp2((m - mn) * cexp);
        m = mn;
        lsum *= corr;
        #pragma unroll
        for (int r = 0; r < 16; r++) {
          const float cr = lanepull(corr, (r & 3) + 8 * (r >> 2) + 4 * hi);
          o0[r] *= cr; o1[r] *= cr;
        }
      }
      const float mc = m * cexp;
      f32x16 p0, p1;
      float ps = 0.f;
      #pragma unroll
      for (int r = 0; r < 16; r++) { p0[r] = vexp2(fmaf(s0[r], cexp, -mc)); ps += p0[r]; }
      #pragma unroll
      for (int r = 0; r < 16; r++) { p1[r] = vexp2(fmaf(s1[r], cexp, -mc)); ps += p1[r]; }
      lsum += ps;

      // ---- P -> bf16 A-fragments (in-register, partner exchange) ----
      auto mk_pa = [&](const f32x16& pp, int base) -> bf16x8 {
        const unsigned a0 = cvtpk(pp[base + 0], pp[base + 1]);
        const unsigned a1 = cvtpk(pp[base + 2], pp[base + 3]);
        const unsigned b0 = cvtpk(pp[base + 4], pp[base + 5]);
        const unsigned b1 = cvtpk(pp[base + 6], pp[base + 7]);
        const unsigned xa0 = __shfl_xor(a0, 32), xa1 = __shfl_xor(a1, 32);
        const unsigned xb0 = __shfl_xor(b0, 32), xb1 = __shfl_xor(b1, 32);
        union { unsigned u[4]; bf16x8 v; } pu;
        pu.u[0] = hi ? xb0 : a0;
        pu.u[1] = hi ? xb1 : a1;
        pu.u[2] = hi ? b0  : xa0;
        pu.u[3] = hi ? b1  : xa1;
        return pu.v;
      };
      bf16x8 pa[4];
      pa[0] = mk_pa(p0, 0); pa[1] = mk_pa(p0, 8);
      pa[2] = mk_pa(p1, 0); pa[3] = mk_pa(p1, 8);

      // ---- O += P V  (VT rows read as b128, same pattern as K) ----
      #pragma unroll
      for (int k16 = 0; k16 < 4; k16++) {
        const int slot = k16 * 2 + hi;
        const bf16x8 vb0 = *(const bf16x8*)(Vb + li * 128 + ((slot ^ swz8(li)) * 16));
        const bf16x8 vb1 = *(const bf16x8*)(Vb + (32 + li) * 128 + ((slot ^ swz8(32 + li)) * 16));
        o0 = __builtin_amdgcn_mfma_f32_32x32x16_bf16(pa[k16], vb0, o0, 0, 0, 0);
        o1 = __builtin_amdgcn_mfma_f32_32x32x16_bf16(pa[k16], vb1, o1, 0, 0, 0);
      }
    }

    if (pre) vwrite(vnext, smem + (cur ^ 1) * 16384 + 8192);  // V landed during compute
    __syncthreads();
  }

  // ---- epilogue: O / l, merged-head store ----
  const float lt = lsum + __shfl_xor(lsum, 32);
  const float rl = __builtin_amdgcn_rcpf(lt);
  #pragma unroll
  for (int r = 0; r < 16; r++) {
    const int q = (r & 3) + 8 * (r >> 2) + 4 * hi;
    const float rr = lanepull(rl, q);
    unsigned short* op = Out + (size_t)(b * Sn + wq + q) * Dn + h * HD;
    op[li]      = f2bf(o0[r] * rr);
    op[32 + li] = f2bf(o1[r] * rr);
  }
}

// ---------------- tail: string_len -> float ----------------
__global__ void copy_len(const int* __restrict__ slen, float* __restrict__ dst, int n) {
  const int i = threadIdx.x;
  if (i < n) dst[i] = (float)slen[i];
}

extern "C" void kernel_launch(void* const* d_in, const int* in_sizes, int n_in,
                              void* d_out, int out_size, void* d_ws, size_t ws_size,
                              hipStream_t stream) {
  const float* X    = (const float*)d_in[0];
  const int*   slen = (const int*)d_in[1];
  const float* Wqkv = (const float*)d_in[2];
  const float* bqkv = (const float*)d_in[3];
  const float* Wo   = (const float*)d_in[4];
  const float* bo   = (const float*)d_in[5];
  float* out = (float*)d_out;

  char* ws = (char*)d_ws;
  unsigned short* Xb    = (unsigned short*)ws;
  unsigned short* Wtq   = (unsigned short*)(ws + 16777216);
  unsigned short* Wto   = (unsigned short*)(ws + 16777216 + 6291456);
  unsigned short* QKVb  = (unsigned short*)(ws + 16777216 + 6291456 + 2097152);
  unsigned short* Attnb = Xb;

  cvt_f32_bf16<<<dim3(8192), dim3(256), 0, stream>>>(X, Xb, Mrows * Dn);
  transpose_cvt<<<dim3(96, 32), dim3(32, 8), 0, stream>>>(Wqkv, Wtq, Dn, D3);
  transpose_cvt<<<dim3(32, 32), dim3(32, 8), 0, stream>>>(Wo, Wto, Dn, Dn);

  gemm_bt<true><<<dim3(64, 24), dim3(256), 0, stream>>>(Xb, Wtq, bqkv, (void*)QKVb, Mrows, D3, Dn);
  attn_fwd2<<<dim3(64, 8), dim3(512), 0, stream>>>(QKVb, Attnb);
  gemm_bt<false><<<dim3(64, 8), dim3(256), 0, stream>>>(Attnb, Wto, bo, d_out, Mrows, Dn, Dn);
  copy_len<<<dim3(1), dim3(64), 0, stream>>>(slen, out + (size_t)Mrows * Dn, Bn);
}

// Round 8
// 193.752 us; speedup vs baseline: 1.7270x; 1.0011x over previous
//
#include <hip/hip_runtime.h>
#include <stdint.h>

typedef __attribute__((ext_vector_type(8))) short bf16x8;
typedef __attribute__((ext_vector_type(4))) float f32x4;
typedef __attribute__((ext_vector_type(16))) float f32x16;
typedef __attribute__((ext_vector_type(4))) unsigned short u16x4;

static constexpr int Bn = 4, Sn = 2048, Dn = 1024, Hn = 16, HD = 64;
static constexpr int Mrows = Bn * Sn;   // 8192
static constexpr int D3 = 3 * Dn;       // 3072

__device__ __forceinline__ unsigned short f2bf(float f) {
  unsigned int u = __float_as_uint(f);
  u += 0x7FFF + ((u >> 16) & 1);
  return (unsigned short)(u >> 16);
}

__device__ __forceinline__ void gload16(const void* gptr, void* lptr) {
  __builtin_amdgcn_global_load_lds(
      (__attribute__((address_space(1))) void*)gptr,
      (__attribute__((address_space(3))) void*)lptr, 16, 0, 0);
}

__device__ __forceinline__ int swz8(int r) { return (r ^ (r >> 3)) & 7; }
__device__ __forceinline__ int swz4(int r) { return (r ^ (r >> 2)) & 3; }

__device__ __forceinline__ float vexp2(float x) {
#if __has_builtin(__builtin_amdgcn_exp2f)
  return __builtin_amdgcn_exp2f(x);
#else
  return exp2f(x);
#endif
}

__device__ __forceinline__ unsigned cvtpk(float lo, float hi) {
  unsigned r;
  asm("v_cvt_pk_bf16_f32 %0, %1, %2" : "=v"(r) : "v"(lo), "v"(hi));
  return r;
}

__device__ __forceinline__ float lanepull(float v, int srclane) {
  return __int_as_float(__builtin_amdgcn_ds_bpermute(srclane * 4, __float_as_int(v)));
}

// ---------------- elementwise f32 -> bf16 ----------------
__global__ void cvt_f32_bf16(const float* __restrict__ in,
                             unsigned short* __restrict__ out, int n) {
  int i = (blockIdx.x * blockDim.x + threadIdx.x) * 4;
  if (i < n) {
    const float4 v = *(const float4*)(in + i);
    u16x4 o;
    o.x = f2bf(v.x); o.y = f2bf(v.y); o.z = f2bf(v.z); o.w = f2bf(v.w);
    *(u16x4*)(out + i) = o;
  }
}

// ---------------- W [K][N] f32 -> W^T [N][K] bf16 ----------------
__global__ void transpose_cvt(const float* __restrict__ W,
                              unsigned short* __restrict__ Wt, int K, int N) {
  __shared__ float tile[32][33];
  const int n0 = blockIdx.x * 32, k0 = blockIdx.y * 32;
  const int tx = threadIdx.x, ty = threadIdx.y;   // block (32,8)
  #pragma unroll
  for (int j = 0; j < 4; j++)
    tile[ty + 8 * j][tx] = W[(size_t)(k0 + ty + 8 * j) * N + n0 + tx];
  __syncthreads();
  #pragma unroll
  for (int j = 0; j < 4; j++)
    Wt[(size_t)(n0 + ty + 8 * j) * K + k0 + tx] = f2bf(tile[tx][ty + 8 * j]);
}

// ---------------- 128x128 bf16 GEMM, C = A[M,K] @ Bt[N,K]^T + bias ----------------
template<bool BF16_OUT>
__global__ __launch_bounds__(256, 2)
void gemm_bt(const unsigned short* __restrict__ A,
             const unsigned short* __restrict__ Bt,
             const float* __restrict__ bias,
             void* __restrict__ Cout, int Mt, int Nt, int Kt) {
  __shared__ __align__(16) unsigned short ldsA[128 * 32];
  __shared__ __align__(16) unsigned short ldsB[128 * 32];
  const int tid  = threadIdx.x;
  const int w    = tid >> 6;
  const int lane = tid & 63;
  const int wr = w >> 1, wc = w & 1;
  const int lrow = lane & 15, lk = lane >> 4;
  const long brow = (long)blockIdx.x * 128;
  const long bcol = (long)blockIdx.y * 128;

  f32x4 acc[4][4] = {};

  const int srow_w = w * 16 + (lane >> 2);
  const int sslot  = lane & 3;

  for (int k0 = 0; k0 < Kt; k0 += 32) {
    __syncthreads();
    #pragma unroll
    for (int i = 0; i < 2; i++) {
      const int r  = i * 64 + srow_w;
      const int ca = sslot ^ swz4(r);
      gload16(A  + (size_t)(brow + r) * Kt + k0 + ca * 8, ldsA + i * 2048 + w * 512);
      gload16(Bt + (size_t)(bcol + r) * Kt + k0 + ca * 8, ldsB + i * 2048 + w * 512);
    }
    __syncthreads();
    bf16x8 af[4], bfv[4];
    #pragma unroll
    for (int mt = 0; mt < 4; mt++) {
      const int rr = wr * 64 + mt * 16 + lrow;
      af[mt] = *(const bf16x8*)(ldsA + rr * 32 + ((lk ^ swz4(rr)) * 8));
    }
    #pragma unroll
    for (int nt = 0; nt < 4; nt++) {
      const int rr = wc * 64 + nt * 16 + lrow;
      bfv[nt] = *(const bf16x8*)(ldsB + rr * 32 + ((lk ^ swz4(rr)) * 8));
    }
    #pragma unroll
    for (int mt = 0; mt < 4; mt++)
      #pragma unroll
      for (int nt = 0; nt < 4; nt++)
        acc[mt][nt] = __builtin_amdgcn_mfma_f32_16x16x32_bf16(af[mt], bfv[nt], acc[mt][nt], 0, 0, 0);
  }

  #pragma unroll
  for (int nt = 0; nt < 4; nt++) {
    const long col = bcol + wc * 64 + nt * 16 + lrow;
    const float bv = bias[col];
    #pragma unroll
    for (int mt = 0; mt < 4; mt++) {
      #pragma unroll
      for (int r = 0; r < 4; r++) {
        const long row = brow + wr * 64 + mt * 16 + lk * 4 + r;
        const float v = acc[mt][nt][r] + bv;
        if (BF16_OUT)
          ((unsigned short*)Cout)[row * Nt + col] = f2bf(v);
        else
          ((float*)Cout)[row * Nt + col] = v;
      }
    }
  }
}

// ---------------- flash attention, swapped-QK^T, 8-wave paired blocks ----------------
// T4 counted-vmcnt loop: raw s_barrier pairs, prefetch loads stay in flight
// across barriers (never vmcnt(0) in steady state). T5 setprio around MFMA.
// Block: 8 waves (512 thr), one KV stream. Waves 0-3 heavy subtiles, 4-7 light.
// Grid (bh=64, p=8): same-KV blocks land on one XCD (L2-local KV).
// K LDS: [64][64] bf16 swz8-swizzled, gload_lds staged (linear dest).
// V LDS: V^T [64 d][64 kv], same swizzle, reg-staged scatter write (T14 split).
__global__ __launch_bounds__(512, 2)
void attn_fwd2(const unsigned short* __restrict__ QKV,
               unsigned short* __restrict__ Out) {
  __shared__ __align__(128) unsigned char smem[32768]; // 2 x (8K K + 8K VT)
  const int tid  = threadIdx.x;
  const int w    = tid >> 6;
  const int lane = tid & 63;
  const int li = lane & 31, hi = lane >> 5;
  const int bh = blockIdx.x;
  const int b  = bh >> 4, h = bh & 15;
  const int pb = blockIdx.y;            // pair-group 0..7
  const int qs = (w < 4) ? (63 - 4 * pb - w) : (4 * pb + (w - 4));  // 32-row q-subtile
  const int wq = qs * 32;
  const int qrow = wq + li;

  // Q as B-fragments: lane holds Q[q=li][d = ks*16 + hi*8 + j]
  bf16x8 qf[4];
  {
    const unsigned short* qp = QKV + (size_t)(b * Sn + qrow) * D3 + h * HD + hi * 8;
    #pragma unroll
    for (int ks = 0; ks < 4; ks++) qf[ks] = *(const bf16x8*)(qp + ks * 16);
  }

  f32x16 o0 = {}, o1 = {};
  float m = -3.0e38f, lsum = 0.f;
  const float cexp = 0.18033688011112042f;  // (1/8) * log2(e)

  // K stage: each wave stages rows w*8..w*8+7 (1 KB), linear dest + pre-swz src
  auto kstage = [&](int kb, unsigned char* Kb) {
    const int r    = w * 8 + (lane >> 3);
    const int slot = (lane & 7) ^ swz8(r);
    gload16(QKV + (size_t)(b * Sn + kb + r) * D3 + Dn + h * HD + slot * 8,
            Kb + w * 1024);
  };
  const int vkv = tid >> 3;          // 0..63
  const int vd0 = (tid & 7) * 8;
  auto vload = [&](int kb) -> bf16x8 {
    return *(const bf16x8*)(QKV + (size_t)(b * Sn + kb + vkv) * D3 + 2 * Dn + h * HD + vd0);
  };
  auto vwrite = [&](bf16x8 vv, unsigned char* Vb) {
    #pragma unroll
    for (int j = 0; j < 8; j++) {
      const int d = vd0 + j;
      *(unsigned short*)(Vb + d * 128 + ((vkv * 2) ^ (swz8(d) << 4))) = (unsigned short)vv[j];
    }
  };

  // prologue: K(0) in flight (counted in loop), V(0) written now
  kstage(0, smem);
  {
    bf16x8 v0 = vload(0);
    vwrite(v0, smem + 8192);
  }
  asm volatile("s_waitcnt lgkmcnt(0)");
  __builtin_amdgcn_sched_barrier(0);

  const int nt = ((63 - 4 * pb) >> 1) + 1;  // tiles for heaviest subtile
  for (int t = 0; t < nt; t++) {
    const int kb  = t << 6;
    const int cur = t & 1;
    unsigned char* Kb = smem + cur * 16384;
    unsigned char* Vb = Kb + 8192;
    const bool pre = (t + 1 < nt);
    bf16x8 vnext;

    // barrier #1: retires t-1 (all waves done with cur^1 buffers)
    __builtin_amdgcn_s_barrier();
    if (pre) {
      kstage(kb + 64, smem + (cur ^ 1) * 16384);   // async into LDS (cur^1)
      vnext = vload(kb + 64);                      // async into regs
      asm volatile("s_waitcnt vmcnt(2)");          // K(t) done; t+1 loads in flight
    } else {
      asm volatile("s_waitcnt vmcnt(0)");
    }
    __builtin_amdgcn_sched_barrier(0);
    __builtin_amdgcn_s_barrier();                  // barrier #2: K(t) visible block-wide

    if (kb <= wq + 31) {  // wave-uniform activity test
      // ---- S^T = K Q^T : lane holds S^T[kv=crow(r,hi)+32t][q=li] ----
      f32x16 s0 = {}, s1 = {};
      __builtin_amdgcn_s_setprio(1);
      #pragma unroll
      for (int ks = 0; ks < 4; ks++) {
        const int slot = ks * 2 + hi;
        const bf16x8 k0 = *(const bf16x8*)(Kb + li * 128 + ((slot ^ swz8(li)) * 16));
        const bf16x8 k1 = *(const bf16x8*)(Kb + (32 + li) * 128 + ((slot ^ swz8(32 + li)) * 16));
        s0 = __builtin_amdgcn_mfma_f32_32x32x16_bf16(k0, qf[ks], s0, 0, 0, 0);
        s1 = __builtin_amdgcn_mfma_f32_32x32x16_bf16(k1, qf[ks], s1, 0, 0, 0);
      }
      __builtin_amdgcn_s_setprio(0);
      // ---- causal mask: only the diagonal tile needs it ----
      if (kb + 63 > wq) {
        #pragma unroll
        for (int r = 0; r < 16; r++) {
          const int kvl = (r & 3) + 8 * (r >> 2) + 4 * hi;
          if (kb + kvl > qrow)      s0[r] = -3.0e38f;
          if (kb + 32 + kvl > qrow) s1[r] = -3.0e38f;
        }
      }
      // ---- online softmax, lane-local row ----
      float tmax = -3.0e38f;
      #pragma unroll
      for (int r = 0; r < 16; r++) tmax = fmaxf(tmax, fmaxf(s0[r], s1[r]));
      tmax = fmaxf(tmax, __shfl_xor(tmax, 32));
      if (__any(tmax > m + 44.0f)) {   // defer-max, 44 raw ~ 8 log2 units
        const float mn   = fmaxf(m, tmax);
        const float corr = vexp2((m - mn) * cexp);
        m = mn;
        lsum *= corr;
        #pragma unroll
        for (int r = 0; r < 16; r++) {
          const float cr = lanepull(corr, (r & 3) + 8 * (r >> 2) + 4 * hi);
          o0[r] *= cr; o1[r] *= cr;
        }
      }
      const float mc = m * cexp;
      f32x16 p0, p1;
      float ps = 0.f;
      #pragma unroll
      for (int r = 0; r < 16; r++) { p0[r] = vexp2(fmaf(s0[r], cexp, -mc)); ps += p0[r]; }
      #pragma unroll
      for (int r = 0; r < 16; r++) { p1[r] = vexp2(fmaf(s1[r], cexp, -mc)); ps += p1[r]; }
      lsum += ps;

      // ---- P -> bf16 A-fragments (in-register, partner exchange) ----
      auto mk_pa = [&](const f32x16& pp, int base) -> bf16x8 {
        const unsigned a0 = cvtpk(pp[base + 0], pp[base + 1]);
        const unsigned a1 = cvtpk(pp[base + 2], pp[base + 3]);
        const unsigned b0 = cvtpk(pp[base + 4], pp[base + 5]);
        const unsigned b1 = cvtpk(pp[base + 6], pp[base + 7]);
        const unsigned xa0 = __shfl_xor(a0, 32), xa1 = __shfl_xor(a1, 32);
        const unsigned xb0 = __shfl_xor(b0, 32), xb1 = __shfl_xor(b1, 32);
        union { unsigned u[4]; bf16x8 v; } pu;
        pu.u[0] = hi ? xb0 : a0;
        pu.u[1] = hi ? xb1 : a1;
        pu.u[2] = hi ? b0  : xa0;
        pu.u[3] = hi ? b1  : xa1;
        return pu.v;
      };
      bf16x8 pa[4];
      pa[0] = mk_pa(p0, 0); pa[1] = mk_pa(p0, 8);
      pa[2] = mk_pa(p1, 0); pa[3] = mk_pa(p1, 8);

      // ---- O += P V  (VT rows read as b128, same pattern as K) ----
      __builtin_amdgcn_s_setprio(1);
      #pragma unroll
      for (int k16 = 0; k16 < 4; k16++) {
        const int slot = k16 * 2 + hi;
        const bf16x8 vb0 = *(const bf16x8*)(Vb + li * 128 + ((slot ^ swz8(li)) * 16));
        const bf16x8 vb1 = *(const bf16x8*)(Vb + (32 + li) * 128 + ((slot ^ swz8(32 + li)) * 16));
        o0 = __builtin_amdgcn_mfma_f32_32x32x16_bf16(pa[k16], vb0, o0, 0, 0, 0);
        o1 = __builtin_amdgcn_mfma_f32_32x32x16_bf16(pa[k16], vb1, o1, 0, 0, 0);
      }
      __builtin_amdgcn_s_setprio(0);
    }

    if (pre) vwrite(vnext, smem + (cur ^ 1) * 16384 + 8192);  // V landed during compute
    asm volatile("s_waitcnt lgkmcnt(0)");
    __builtin_amdgcn_sched_barrier(0);
  }

  // ---- epilogue: O / l, merged-head store ----
  const float lt = lsum + __shfl_xor(lsum, 32);
  const float rl = __builtin_amdgcn_rcpf(lt);
  #pragma unroll
  for (int r = 0; r < 16; r++) {
    const int q = (r & 3) + 8 * (r >> 2) + 4 * hi;
    const float rr = lanepull(rl, q);
    unsigned short* op = Out + (size_t)(b * Sn + wq + q) * Dn + h * HD;
    op[li]      = f2bf(o0[r] * rr);
    op[32 + li] = f2bf(o1[r] * rr);
  }
}

// ---------------- tail: string_len -> float ----------------
__global__ void copy_len(const int* __restrict__ slen, float* __restrict__ dst, int n) {
  const int i = threadIdx.x;
  if (i < n) dst[i] = (float)slen[i];
}

extern "C" void kernel_launch(void* const* d_in, const int* in_sizes, int n_in,
                              void* d_out, int out_size, void* d_ws, size_t ws_size,
                              hipStream_t stream) {
  const float* X    = (const float*)d_in[0];
  const int*   slen = (const int*)d_in[1];
  const float* Wqkv = (const float*)d_in[2];
  const float* bqkv = (const float*)d_in[3];
  const float* Wo   = (const float*)d_in[4];
  const float* bo   = (const float*)d_in[5];
  float* out = (float*)d_out;

  char* ws = (char*)d_ws;
  unsigned short* Xb    = (unsigned short*)ws;
  unsigned short* Wtq   = (unsigned short*)(ws + 16777216);
  unsigned short* Wto   = (unsigned short*)(ws + 16777216 + 6291456);
  unsigned short* QKVb  = (unsigned short*)(ws + 16777216 + 6291456 + 2097152);
  unsigned short* Attnb = Xb;

  cvt_f32_bf16<<<dim3(8192), dim3(256), 0, stream>>>(X, Xb, Mrows * Dn);
  transpose_cvt<<<dim3(96, 32), dim3(32, 8), 0, stream>>>(Wqkv, Wtq, Dn, D3);
  transpose_cvt<<<dim3(32, 32), dim3(32, 8), 0, stream>>>(Wo, Wto, Dn, Dn);

  gemm_bt<true><<<dim3(64, 24), dim3(256), 0, stream>>>(Xb, Wtq, bqkv, (void*)QKVb, Mrows, D3, Dn);
  attn_fwd2<<<dim3(64, 8), dim3(512), 0, stream>>>(QKVb, Attnb);
  gemm_bt<false><<<dim3(64, 8), dim3(256), 0, stream>>>(Attnb, Wto, bo, d_out, Mrows, Dn, Dn);
  copy_len<<<dim3(1), dim3(64), 0, stream>>>(slen, out + (size_t)Mrows * Dn, Bn);
}